// Round 1
// baseline (166.221 us; speedup 1.0000x reference)
//
#include <hip/hip_runtime.h>

typedef unsigned short u16;
typedef __bf16 bf16x8 __attribute__((ext_vector_type(8)));
typedef float f32x4 __attribute__((ext_vector_type(4)));
typedef u16 u16x4 __attribute__((ext_vector_type(4)));

#define S_LEN 2048
#define NH 16
#define DH 64
#define DM 1024

__device__ __forceinline__ u16 f2bf(float f) {
  unsigned u = __float_as_uint(f);
  u += 0x7FFFu + ((u >> 16) & 1u);
  return (u16)(u >> 16);
}
__device__ __forceinline__ float bf2f(u16 h) {
  return __uint_as_float(((unsigned)h) << 16);
}

// ---------------- convert f32 -> bf16 ----------------
__global__ __launch_bounds__(256) void conv_kernel(const float* __restrict__ in,
                                                   u16* __restrict__ out, int n) {
  int i = (blockIdx.x * 256 + threadIdx.x) * 4;
  if (i >= n) return;
  float4 v = *(const float4*)(in + i);
  u16x4 o;
  o.x = f2bf(v.x); o.y = f2bf(v.y); o.z = f2bf(v.z); o.w = f2bf(v.w);
  *(u16x4*)(out + i) = o;
}

// ---------------- bf16 GEMM: C[M][N] = A[M][K] * B[N][K]^T ----------------
// 128x128 tile, BK=32, 4 waves (2x2 of 64x64), reg-staged swizzled LDS.
template <int OUTF32>
__global__ __launch_bounds__(256) void gemm_bt(const u16* __restrict__ A,
                                               const u16* __restrict__ B,
                                               void* __restrict__ C,
                                               int N, int K) {
  __shared__ __align__(16) unsigned char smem[16384];
  unsigned char* abuf = smem;
  unsigned char* bbuf = smem + 8192;
  int tid = threadIdx.x;
  int w = tid >> 6, l = tid & 63, lg = l >> 4, lr = l & 15;
  int m0 = blockIdx.y * 128, n0 = blockIdx.x * 128;
  int wm = (w >> 1) * 64, wn = (w & 1) * 64;
  int NK = K >> 5;

  int crow[2], csl[2];
#pragma unroll
  for (int i = 0; i < 2; ++i) {
    int c = i * 256 + tid;
    crow[i] = c >> 2;      // row 0..127
    csl[i] = c & 3;        // 16B slot within 64B row
  }
  bf16x8 ra[2], rb[2];
  auto stage_load = [&](int kt) {
#pragma unroll
    for (int i = 0; i < 2; ++i) {
      ra[i] = *(const bf16x8*)(A + (size_t)(m0 + crow[i]) * K + kt * 32 + csl[i] * 8);
      rb[i] = *(const bf16x8*)(B + (size_t)(n0 + crow[i]) * K + kt * 32 + csl[i] * 8);
    }
  };
  stage_load(0);

  f32x4 zero4 = {0.f, 0.f, 0.f, 0.f};
  f32x4 acc[4][4];
#pragma unroll
  for (int mt = 0; mt < 4; ++mt)
#pragma unroll
    for (int nt = 0; nt < 4; ++nt) acc[mt][nt] = zero4;

  for (int kt = 0; kt < NK; ++kt) {
    __syncthreads();  // previous iter's readers done
#pragma unroll
    for (int i = 0; i < 2; ++i) {
      int row = crow[i];
      int sp = (csl[i] ^ row ^ (row >> 2)) & 3;
      *(bf16x8*)(abuf + row * 64 + sp * 16) = ra[i];
      *(bf16x8*)(bbuf + row * 64 + sp * 16) = rb[i];
    }
    if (kt + 1 < NK) stage_load(kt + 1);
    __syncthreads();  // staged tile visible

    bf16x8 af[4], bfr[4];
#pragma unroll
    for (int mt = 0; mt < 4; ++mt) {
      int row = wm + mt * 16 + lr;
      int sp = (lg ^ row ^ (row >> 2)) & 3;
      af[mt] = *(const bf16x8*)(abuf + row * 64 + sp * 16);
    }
#pragma unroll
    for (int nt = 0; nt < 4; ++nt) {
      int row = wn + nt * 16 + lr;
      int sp = (lg ^ row ^ (row >> 2)) & 3;
      bfr[nt] = *(const bf16x8*)(bbuf + row * 64 + sp * 16);
    }
#pragma unroll
    for (int mt = 0; mt < 4; ++mt)
#pragma unroll
      for (int nt = 0; nt < 4; ++nt)
        acc[mt][nt] = __builtin_amdgcn_mfma_f32_16x16x32_bf16(af[mt], bfr[nt], acc[mt][nt], 0, 0, 0);
  }

#pragma unroll
  for (int mt = 0; mt < 4; ++mt)
#pragma unroll
    for (int nt = 0; nt < 4; ++nt)
#pragma unroll
      for (int r = 0; r < 4; ++r) {
        int row = m0 + wm + mt * 16 + lg * 4 + r;
        int col = n0 + wn + nt * 16 + lr;
        float v = acc[mt][nt][r];
        if (OUTF32) ((float*)C)[(size_t)row * N + col] = v;
        else        ((u16*)C)[(size_t)row * N + col] = f2bf(v);
      }
}

// ---------------- RoPE + head-major layout + V transpose ----------------
__global__ __launch_bounds__(256) void rope_kernel(const u16* __restrict__ qkv,
                                                   const float* __restrict__ pi_gate_logit,
                                                   u16* __restrict__ qrot,
                                                   u16* __restrict__ krot,
                                                   u16* __restrict__ vt) {
  int st = blockIdx.x;   // s tile (0..31)
  int bh = blockIdx.y;   // b*16+h
  int h = bh & 15;
  int t = threadIdx.x;
  int sl = t >> 2;       // 0..63
  int pb = t & 3;
  int d0 = pb * 16;
  int s = st * 64 + sl;
  int b = bh >> 4;
  size_t rowg = (size_t)(b * S_LEN + s) * (3 * DM) + h * DH + d0;

  float pg = 1.0f / (1.0f + __expf(-pi_gate_logit[h]));
  float spos = (float)s;
  float cs[8], sn[8];
#pragma unroll
  for (int j = 0; j < 8; ++j) {
    float p = (float)(pb * 8 + j);
    float fr = exp2f((1.0f - p * 0.03125f) * 1.6514961294723187f);  // pi^(1-p/32)
    float th = (spos * fr) * pg;
    float rev = th * 0.15915494309189535f;
    rev = rev - floorf(rev);
    cs[j] = __builtin_amdgcn_cosf(rev);
    sn[j] = __builtin_amdgcn_sinf(rev);
  }

#pragma unroll
  for (int which = 0; which < 2; ++which) {
    const u16* src = qkv + rowg + (size_t)which * DM;
    u16 in[16], ou[16];
    *(bf16x8*)(in)     = *(const bf16x8*)(src);
    *(bf16x8*)(in + 8) = *(const bf16x8*)(src + 8);
#pragma unroll
    for (int j = 0; j < 8; ++j) {
      float t1 = bf2f(in[2 * j]), t2 = bf2f(in[2 * j + 1]);
      ou[2 * j]     = f2bf(t1 * cs[j] - t2 * sn[j]);
      ou[2 * j + 1] = f2bf(t1 * sn[j] + t2 * cs[j]);
    }
    u16* dst = (which ? krot : qrot) + ((size_t)bh * S_LEN + s) * DH + d0;
    *(bf16x8*)(dst)     = *(bf16x8*)(ou);
    *(bf16x8*)(dst + 8) = *(bf16x8*)(ou + 8);
  }

  {
    const u16* src = qkv + rowg + 2 * DM;
    u16 in[16];
    *(bf16x8*)(in)     = *(const bf16x8*)(src);
    *(bf16x8*)(in + 8) = *(const bf16x8*)(src + 8);
#pragma unroll
    for (int e = 0; e < 16; ++e)
      vt[((size_t)bh * DH + d0 + e) * S_LEN + st * 64 + sl] = in[e];
  }
}

// ---------------- flash attention (causal + linear decay bias) ----------------
__global__ __launch_bounds__(256) void attn_kernel(const u16* __restrict__ qrot,
                                                   const u16* __restrict__ krot,
                                                   const u16* __restrict__ vt,
                                                   const float* __restrict__ log_xi,
                                                   const float* __restrict__ e_gate_logit,
                                                   u16* __restrict__ attnout) {
  int bh = blockIdx.x, qt = blockIdx.y;
  int b = bh >> 4, h = bh & 15;
  int tid = threadIdx.x, w = tid >> 6, l = tid & 63, lg = l >> 4, lr = l & 15;
  int q0 = qt * 64;

  float eg = 1.0f / (1.0f + __expf(-e_gate_logit[h]));
  float cdec = eg * __expf(-log_xi[h]);  // e_g / xi

  __shared__ __align__(16) unsigned char smem[24576];
  unsigned char* kbuf = smem;
  unsigned char* vbuf = smem + 8192;
  unsigned char* pbuf = smem + 16384 + (w << 11);  // 2KB per wave

  bf16x8 qf[2];
  {
    const u16* qp = qrot + ((size_t)bh * S_LEN + q0 + w * 16 + lr) * DH + lg * 8;
    qf[0] = *(const bf16x8*)(qp);
    qf[1] = *(const bf16x8*)(qp + 32);
  }

  f32x4 zero4 = {0.f, 0.f, 0.f, 0.f};
  f32x4 oacc[4];
  float mrun[4], lrun[4];
#pragma unroll
  for (int nt = 0; nt < 4; ++nt) oacc[nt] = zero4;
#pragma unroll
  for (int r = 0; r < 4; ++r) { mrun[r] = -1e30f; lrun[r] = 0.f; }

  for (int t = 0; t <= qt; ++t) {
    bf16x8 kr[2], vr[2];
#pragma unroll
    for (int i = 0; i < 2; ++i) {
      int c = i * 256 + tid, row = c >> 3, slt = c & 7;
      kr[i] = *(const bf16x8*)(krot + ((size_t)bh * S_LEN + t * 64 + row) * DH + slt * 8);
      vr[i] = *(const bf16x8*)(vt + ((size_t)bh * DH + row) * S_LEN + t * 64 + slt * 8);
    }
    __syncthreads();
#pragma unroll
    for (int i = 0; i < 2; ++i) {
      int c = i * 256 + tid, row = c >> 3, slt = c & 7;
      int sp = slt ^ (row & 7);
      *(bf16x8*)(kbuf + row * 128 + sp * 16) = kr[i];
      *(bf16x8*)(vbuf + row * 128 + sp * 16) = vr[i];
    }
    __syncthreads();

    // S = Q K^T  (per wave: 16 q-rows x 64 kv)
    f32x4 sacc[4];
#pragma unroll
    for (int nt = 0; nt < 4; ++nt) sacc[nt] = zero4;
#pragma unroll
    for (int nt = 0; nt < 4; ++nt)
#pragma unroll
      for (int kk = 0; kk < 2; ++kk) {
        int row = nt * 16 + lr;
        int sl_ = lg + kk * 4;
        bf16x8 kf = *(const bf16x8*)(kbuf + row * 128 + ((sl_ ^ (row & 7)) << 4));
        sacc[nt] = __builtin_amdgcn_mfma_f32_16x16x32_bf16(qf[kk], kf, sacc[nt], 0, 0, 0);
      }

    // masked, biased scores + online softmax
    float pv[4][4], rmax[4];
    int ibase = q0 + w * 16 + lg * 4;
#pragma unroll
    for (int r = 0; r < 4; ++r) rmax[r] = -1e30f;
#pragma unroll
    for (int nt = 0; nt < 4; ++nt) {
      int j = t * 64 + nt * 16 + lr;
#pragma unroll
      for (int r = 0; r < 4; ++r) {
        int i = ibase + r;
        float sv = (j <= i) ? sacc[nt][r] * 0.125f - (float)(i - j) * cdec : -1e30f;
        pv[nt][r] = sv;
        rmax[r] = fmaxf(rmax[r], sv);
      }
    }
#pragma unroll
    for (int r = 0; r < 4; ++r) {
      float v = rmax[r];
      v = fmaxf(v, __shfl_xor(v, 1));
      v = fmaxf(v, __shfl_xor(v, 2));
      v = fmaxf(v, __shfl_xor(v, 4));
      v = fmaxf(v, __shfl_xor(v, 8));
      rmax[r] = v;
    }
    float fac[4], rsum[4];
#pragma unroll
    for (int r = 0; r < 4; ++r) {
      float mnew = fmaxf(mrun[r], rmax[r]);
      fac[r] = __expf(mrun[r] - mnew);
      mrun[r] = mnew;
      rsum[r] = 0.f;
    }
#pragma unroll
    for (int nt = 0; nt < 4; ++nt)
#pragma unroll
      for (int r = 0; r < 4; ++r) {
        float p = __expf(pv[nt][r] - mrun[r]);
        pv[nt][r] = p;
        rsum[r] += p;
      }
#pragma unroll
    for (int r = 0; r < 4; ++r) {
      float v = rsum[r];
      v += __shfl_xor(v, 1);
      v += __shfl_xor(v, 2);
      v += __shfl_xor(v, 4);
      v += __shfl_xor(v, 8);
      lrun[r] = lrun[r] * fac[r] + v;
    }

    // P (accum layout) -> per-wave LDS (swizzled) -> A-fragments
#pragma unroll
    for (int nt = 0; nt < 4; ++nt)
#pragma unroll
      for (int r = 0; r < 4; ++r) {
        int prow = lg * 4 + r;
        int pcol = nt * 16 + lr;
        *(u16*)(pbuf + ((prow * 128 + pcol * 2) ^ ((prow & 7) << 4))) = f2bf(pv[nt][r]);
      }
    asm volatile("s_waitcnt lgkmcnt(0)" ::: "memory");

#pragma unroll
    for (int nt = 0; nt < 4; ++nt)
#pragma unroll
      for (int r = 0; r < 4; ++r) oacc[nt][r] *= fac[r];

    bf16x8 pf[2];
#pragma unroll
    for (int kk = 0; kk < 2; ++kk) {
      int sl_ = lg + kk * 4;
      pf[kk] = *(const bf16x8*)(pbuf + lr * 128 + ((sl_ ^ (lr & 7)) << 4));
    }
#pragma unroll
    for (int nt = 0; nt < 4; ++nt)
#pragma unroll
      for (int kk = 0; kk < 2; ++kk) {
        int row = nt * 16 + lr;
        int sl_ = lg + kk * 4;
        bf16x8 vf = *(const bf16x8*)(vbuf + row * 128 + ((sl_ ^ (row & 7)) << 4));
        oacc[nt] = __builtin_amdgcn_mfma_f32_16x16x32_bf16(pf[kk], vf, oacc[nt], 0, 0, 0);
      }
  }

#pragma unroll
  for (int nt = 0; nt < 4; ++nt)
#pragma unroll
    for (int r = 0; r < 4; ++r) {
      int srow = q0 + w * 16 + lg * 4 + r;
      int col = h * DH + nt * 16 + lr;
      float v = oacc[nt][r] / lrun[r];
      attnout[((size_t)b * S_LEN + srow) * DM + col] = f2bf(v);
    }
}

// ---------------- launch ----------------
extern "C" void kernel_launch(void* const* d_in, const int* in_sizes, int n_in,
                              void* d_out, int out_size, void* d_ws, size_t ws_size,
                              hipStream_t stream) {
  const float* x    = (const float*)d_in[0];
  const float* Wqkv = (const float*)d_in[1];
  const float* Wo   = (const float*)d_in[2];
  const float* log_xi        = (const float*)d_in[3];
  const float* pi_gate_logit = (const float*)d_in[4];
  const float* e_gate_logit  = (const float*)d_in[5];

  u16* xb     = (u16*)d_ws;                 // 4096x1024
  u16* wqkvb  = xb + 4194304;               // 3072x1024
  u16* wob    = wqkvb + 3145728;            // 1024x1024
  u16* qkv    = wob + 1048576;              // 4096x3072
  u16* qrot   = qkv + 12582912;             // 32x2048x64
  u16* krot   = qrot + 4194304;
  u16* vt     = krot + 4194304;             // 32x64x2048
  u16* attno  = vt + 4194304;               // 4096x1024

  conv_kernel<<<4096, 256, 0, stream>>>(x, xb, 4194304);
  conv_kernel<<<3072, 256, 0, stream>>>(Wqkv, wqkvb, 3145728);
  conv_kernel<<<1024, 256, 0, stream>>>(Wo, wob, 1048576);

  gemm_bt<0><<<dim3(24, 32), 256, 0, stream>>>(xb, wqkvb, qkv, 3072, 1024);

  rope_kernel<<<dim3(32, 32), 256, 0, stream>>>(qkv, pi_gate_logit, qrot, krot, vt);

  attn_kernel<<<dim3(32, 32), 256, 0, stream>>>(qrot, krot, vt, log_xi, e_gate_logit, attno);

  gemm_bt<1><<<dim3(8, 32), 256, 0, stream>>>(attno, wob, d_out, 1024, 1024);
}

// Round 2
// 137.463 us; speedup vs baseline: 1.2092x; 1.2092x over previous
//
#include <hip/hip_runtime.h>

typedef unsigned short u16;
typedef unsigned int u32;
typedef __bf16 bf16x8 __attribute__((ext_vector_type(8)));
typedef float f32x4 __attribute__((ext_vector_type(4)));
typedef u16 u16x4 __attribute__((ext_vector_type(4)));

#define S_LEN 2048
#define NH 16
#define DH 64
#define DM 1024

#define GLDS(gp, lp) __builtin_amdgcn_global_load_lds( \
    (const __attribute__((address_space(1))) void*)(gp), \
    (__attribute__((address_space(3))) void*)(lp), 16, 0, 0)

__device__ __forceinline__ u16 f2bf(float f) {
  unsigned u = __float_as_uint(f);
  u += 0x7FFFu + ((u >> 16) & 1u);
  return (u16)(u >> 16);
}
__device__ __forceinline__ float bf2f(u16 h) {
  return __uint_as_float(((unsigned)h) << 16);
}

// ---------------- convert f32 -> bf16 ----------------
__global__ __launch_bounds__(256) void conv_kernel(const float* __restrict__ in,
                                                   u16* __restrict__ out, int n) {
  int i = (blockIdx.x * 256 + threadIdx.x) * 4;
  if (i >= n) return;
  float4 v = *(const float4*)(in + i);
  u16x4 o;
  o.x = f2bf(v.x); o.y = f2bf(v.y); o.z = f2bf(v.z); o.w = f2bf(v.w);
  *(u16x4*)(out + i) = o;
}

// ---------------- bf16 GEMM: C[M][N] = A[M][K] * B[N][K]^T ----------------
// 128x128 tile, BK=32, 4 waves, global_load_lds width-16 staging (m97 pattern).
template <int OUTF32>
__global__ __launch_bounds__(256) void gemm_bt(const u16* __restrict__ A,
                                               const u16* __restrict__ B,
                                               void* __restrict__ C,
                                               int N, int K) {
  __shared__ __align__(16) u16 smem[8192];
  u16* abuf = smem;
  u16* bbuf = smem + 4096;
  int tid = threadIdx.x;
  int w = tid >> 6, l = tid & 63, lg = l >> 4, lr = l & 15;
  int m0 = blockIdx.y * 128, n0 = blockIdx.x * 128;
  int wm = (w >> 1) * 64, wn = (w & 1) * 64;
  int NK = K >> 5;

  int srow[2], scol[2];
#pragma unroll
  for (int i = 0; i < 2; ++i) {
    srow[i] = (i * 4 + w) * 16 + (l >> 2);
    scol[i] = (l & 3) * 8;
  }

  f32x4 zero4 = {0.f, 0.f, 0.f, 0.f};
  f32x4 acc[4][4];
#pragma unroll
  for (int mt = 0; mt < 4; ++mt)
#pragma unroll
    for (int nt = 0; nt < 4; ++nt) acc[mt][nt] = zero4;

  for (int kt = 0; kt < NK; ++kt) {
    __syncthreads();  // previous iter's readers done
#pragma unroll
    for (int i = 0; i < 2; ++i) {
      GLDS(A + (size_t)(m0 + srow[i]) * K + kt * 32 + scol[i], abuf + (i * 4 + w) * 512);
      GLDS(B + (size_t)(n0 + srow[i]) * K + kt * 32 + scol[i], bbuf + (i * 4 + w) * 512);
    }
    __syncthreads();  // staged tile visible (vmcnt drained by sync)

    bf16x8 af[4], bfr[4];
#pragma unroll
    for (int mt = 0; mt < 4; ++mt)
      af[mt] = *(const bf16x8*)(abuf + (wm + mt * 16 + lr) * 32 + lg * 8);
#pragma unroll
    for (int nt = 0; nt < 4; ++nt)
      bfr[nt] = *(const bf16x8*)(bbuf + (wn + nt * 16 + lr) * 32 + lg * 8);
    __builtin_amdgcn_s_setprio(1);
#pragma unroll
    for (int mt = 0; mt < 4; ++mt)
#pragma unroll
      for (int nt = 0; nt < 4; ++nt)
        acc[mt][nt] = __builtin_amdgcn_mfma_f32_16x16x32_bf16(af[mt], bfr[nt], acc[mt][nt], 0, 0, 0);
    __builtin_amdgcn_s_setprio(0);
  }

#pragma unroll
  for (int mt = 0; mt < 4; ++mt)
#pragma unroll
    for (int nt = 0; nt < 4; ++nt)
#pragma unroll
      for (int r = 0; r < 4; ++r) {
        int row = m0 + wm + mt * 16 + lg * 4 + r;
        int col = n0 + wn + nt * 16 + lr;
        float v = acc[mt][nt][r];
        if (OUTF32) ((float*)C)[(size_t)row * N + col] = v;
        else        ((u16*)C)[(size_t)row * N + col] = f2bf(v);
      }
}

// ---------------- RoPE + head-major layout + V transpose ----------------
// Q is pre-scaled by 1/sqrt(dh) = 0.125 here.
__global__ __launch_bounds__(256) void rope_kernel(const u16* __restrict__ qkv,
                                                   const float* __restrict__ pi_gate_logit,
                                                   u16* __restrict__ qrot,
                                                   u16* __restrict__ krot,
                                                   u16* __restrict__ vt) {
  int st = blockIdx.x;   // s tile (0..31)
  int bh = blockIdx.y;   // b*16+h
  int h = bh & 15;
  int t = threadIdx.x;
  int sl = t >> 2;       // 0..63
  int pb = t & 3;
  int d0 = pb * 16;
  int s = st * 64 + sl;
  int b = bh >> 4;
  size_t rowg = (size_t)(b * S_LEN + s) * (3 * DM) + h * DH + d0;

  float pg = 1.0f / (1.0f + __expf(-pi_gate_logit[h]));
  float spos = (float)s;
  float cs[8], sn[8];
#pragma unroll
  for (int j = 0; j < 8; ++j) {
    float p = (float)(pb * 8 + j);
    float fr = exp2f((1.0f - p * 0.03125f) * 1.6514961294723187f);  // pi^(1-p/32)
    float th = (spos * fr) * pg;
    float rev = th * 0.15915494309189535f;
    rev = rev - floorf(rev);
    cs[j] = __builtin_amdgcn_cosf(rev);
    sn[j] = __builtin_amdgcn_sinf(rev);
  }

#pragma unroll
  for (int which = 0; which < 2; ++which) {
    const u16* src = qkv + rowg + (size_t)which * DM;
    float sc = which ? 1.0f : 0.125f;
    u16 in[16], ou[16];
    *(bf16x8*)(in)     = *(const bf16x8*)(src);
    *(bf16x8*)(in + 8) = *(const bf16x8*)(src + 8);
#pragma unroll
    for (int j = 0; j < 8; ++j) {
      float t1 = bf2f(in[2 * j]), t2 = bf2f(in[2 * j + 1]);
      ou[2 * j]     = f2bf((t1 * cs[j] - t2 * sn[j]) * sc);
      ou[2 * j + 1] = f2bf((t1 * sn[j] + t2 * cs[j]) * sc);
    }
    u16* dst = (which ? krot : qrot) + ((size_t)bh * S_LEN + s) * DH + d0;
    *(bf16x8*)(dst)     = *(bf16x8*)(ou);
    *(bf16x8*)(dst + 8) = *(bf16x8*)(ou + 8);
  }

  {
    const u16* src = qkv + rowg + 2 * DM;
    u16 in[16];
    *(bf16x8*)(in)     = *(const bf16x8*)(src);
    *(bf16x8*)(in + 8) = *(const bf16x8*)(src + 8);
#pragma unroll
    for (int e = 0; e < 16; ++e)
      vt[((size_t)bh * DH + d0 + e) * S_LEN + st * 64 + sl] = in[e];
  }
}

// ---------------- flash attention (causal + linear decay bias) ----------------
// Swapped QK^T (S^T = K.Q^T) so each lane owns one q-row: in-lane softmax.
// Block handles q-tiles {pr, 31-pr} for load balance.
__global__ __launch_bounds__(256) void attn_kernel(const u16* __restrict__ qrot,
                                                   const u16* __restrict__ krot,
                                                   const u16* __restrict__ vt,
                                                   const float* __restrict__ log_xi,
                                                   const float* __restrict__ e_gate_logit,
                                                   u16* __restrict__ attnout) {
  int bh = blockIdx.x, pr = blockIdx.y;
  int b = bh >> 4, h = bh & 15;
  int tid = threadIdx.x, w = tid >> 6, l = tid & 63, lg = l >> 4, lr = l & 15;

  float eg = 1.0f / (1.0f + __expf(-e_gate_logit[h]));
  float cdec = eg * __expf(-log_xi[h]);  // e_g / xi

  __shared__ __align__(16) unsigned char smem[24576];
  unsigned char* kbuf = smem;
  unsigned char* vbuf = smem + 8192;
  unsigned char* pbuf = smem + 16384 + (w << 11);  // 2KB per wave

  const size_t bhS = (size_t)bh * S_LEN;
  f32x4 zero4 = {0.f, 0.f, 0.f, 0.f};

  for (int pass = 0; pass < 2; ++pass) {
    int qt = pass ? (31 - pr) : pr;
    int q0 = qt * 64;
    int iql = w * 16 + lr;  // q-row local to tile, this lane's row

    bf16x8 qf[2];
    {
      const u16* qp = qrot + (bhS + q0 + iql) * DH + lg * 8;
      qf[0] = *(const bf16x8*)(qp);
      qf[1] = *(const bf16x8*)(qp + 32);
    }

    f32x4 oacc[4];
#pragma unroll
    for (int nt = 0; nt < 4; ++nt) oacc[nt] = zero4;
    float mrun = -1e30f, lrun = 0.f;

    bf16x8 kr[2], vr[2];
#pragma unroll
    for (int i = 0; i < 2; ++i) {
      int c = i * 256 + tid, row = c >> 3, slt = c & 7;
      kr[i] = *(const bf16x8*)(krot + (bhS + row) * DH + slt * 8);
      vr[i] = *(const bf16x8*)(vt + ((size_t)bh * DH + row) * S_LEN + slt * 8);
    }

    for (int t = 0; t <= qt; ++t) {
      __syncthreads();  // prior readers done; prefetched loads drained here
#pragma unroll
      for (int i = 0; i < 2; ++i) {
        int c = i * 256 + tid, row = c >> 3, slt = c & 7;
        int sp = slt ^ (row & 7);
        *(bf16x8*)(kbuf + row * 128 + sp * 16) = kr[i];
        *(bf16x8*)(vbuf + row * 128 + sp * 16) = vr[i];
      }
      __syncthreads();
      if (t < qt) {  // prefetch next KV tile into regs; hides under compute
#pragma unroll
        for (int i = 0; i < 2; ++i) {
          int c = i * 256 + tid, row = c >> 3, slt = c & 7;
          kr[i] = *(const bf16x8*)(krot + (bhS + (t + 1) * 64 + row) * DH + slt * 8);
          vr[i] = *(const bf16x8*)(vt + ((size_t)bh * DH + row) * S_LEN + (t + 1) * 64 + slt * 8);
        }
      }

      // S^T = K.Q^T : sacc[nt] col=lr=q, row=lg*4+r=kv-local
      f32x4 sacc[4];
#pragma unroll
      for (int nt = 0; nt < 4; ++nt) sacc[nt] = zero4;
      __builtin_amdgcn_s_setprio(1);
#pragma unroll
      for (int nt = 0; nt < 4; ++nt)
#pragma unroll
        for (int kk = 0; kk < 2; ++kk) {
          int row = nt * 16 + lr;
          int sl_ = lg + kk * 4;
          bf16x8 kf = *(const bf16x8*)(kbuf + row * 128 + ((sl_ ^ (row & 7)) << 4));
          sacc[nt] = __builtin_amdgcn_mfma_f32_16x16x32_bf16(kf, qf[kk], sacc[nt], 0, 0, 0);
        }
      __builtin_amdgcn_s_setprio(0);

      // scores: s + j*c  (row term -i*c cancels in softmax; 1/8 folded into Q)
      float pv[16];
      float jb = (float)(t * 64 + lg * 4) * cdec;
#pragma unroll
      for (int nt = 0; nt < 4; ++nt)
#pragma unroll
        for (int r = 0; r < 4; ++r) {
          float v = sacc[nt][r] + (jb + (float)(nt * 16) * cdec + (float)r * cdec);
          if (t == qt) {
            int jl = nt * 16 + lg * 4 + r;
            v = (jl <= iql) ? v : -1e30f;
          }
          pv[nt * 4 + r] = v;
        }

      // row max: in-lane tree + 2 shuffles
      float m1 = pv[0];
#pragma unroll
      for (int i = 1; i < 16; ++i) m1 = fmaxf(m1, pv[i]);
      m1 = fmaxf(m1, __shfl_xor(m1, 16));
      m1 = fmaxf(m1, __shfl_xor(m1, 32));

      // defer-max rescale (THR=8)
      if (__ballot(m1 > mrun + 8.f)) {
        float mnew = fmaxf(mrun, m1);
        float fac = __expf(mrun - mnew);
        mrun = mnew;
        lrun *= fac;
        int fi = __float_as_int(fac);
        float facr[4];
#pragma unroll
        for (int r = 0; r < 4; ++r)
          facr[r] = __int_as_float(__builtin_amdgcn_ds_bpermute((4 * lg + r) << 2, fi));
#pragma unroll
        for (int nt = 0; nt < 4; ++nt)
#pragma unroll
          for (int r = 0; r < 4; ++r) oacc[nt][r] *= facr[r];
      }

      // exp + sum
      float p[16];
      float rsum = 0.f;
#pragma unroll
      for (int i = 0; i < 16; ++i) {
        p[i] = __expf(pv[i] - mrun);
        rsum += p[i];
      }
      rsum += __shfl_xor(rsum, 16);
      rsum += __shfl_xor(rsum, 32);
      lrun += rsum;

      // pack P pairs -> per-wave swizzled LDS
#pragma unroll
      for (int nt = 0; nt < 4; ++nt)
#pragma unroll
        for (int rp = 0; rp < 2; ++rp) {
          u32 pk;
          asm("v_cvt_pk_bf16_f32 %0, %1, %2" : "=v"(pk)
              : "v"(p[nt * 4 + 2 * rp]), "v"(p[nt * 4 + 2 * rp + 1]));
          *(u32*)(pbuf + ((lr * 128 + nt * 32 + lg * 8 + rp * 4) ^ ((lr & 7) << 4))) = pk;
        }
      asm volatile("s_waitcnt lgkmcnt(0)" ::: "memory");

      bf16x8 pf[2];
#pragma unroll
      for (int kk = 0; kk < 2; ++kk)
        pf[kk] = *(const bf16x8*)(pbuf + ((lr * 128 + (lg + 4 * kk) * 16) ^ ((lr & 7) << 4)));

      __builtin_amdgcn_s_setprio(1);
#pragma unroll
      for (int nt = 0; nt < 4; ++nt)
#pragma unroll
        for (int kk = 0; kk < 2; ++kk) {
          int row = nt * 16 + lr;
          int sl_ = lg + kk * 4;
          bf16x8 vf = *(const bf16x8*)(vbuf + row * 128 + ((sl_ ^ (row & 7)) << 4));
          oacc[nt] = __builtin_amdgcn_mfma_f32_16x16x32_bf16(pf[kk], vf, oacc[nt], 0, 0, 0);
        }
      __builtin_amdgcn_s_setprio(0);
    }

    // epilogue: redistribute l (lane lr holds q-row lr's sum) and write
    float lfin[4];
    int li = __float_as_int(lrun);
#pragma unroll
    for (int r = 0; r < 4; ++r)
      lfin[r] = __int_as_float(__builtin_amdgcn_ds_bpermute((4 * lg + r) << 2, li));
#pragma unroll
    for (int nt = 0; nt < 4; ++nt)
#pragma unroll
      for (int r = 0; r < 4; ++r) {
        int srow = q0 + w * 16 + lg * 4 + r;
        int col = h * DH + nt * 16 + lr;
        attnout[((size_t)b * S_LEN + srow) * DM + col] = f2bf(oacc[nt][r] / lfin[r]);
      }
  }
}

// ---------------- launch ----------------
extern "C" void kernel_launch(void* const* d_in, const int* in_sizes, int n_in,
                              void* d_out, int out_size, void* d_ws, size_t ws_size,
                              hipStream_t stream) {
  const float* x    = (const float*)d_in[0];
  const float* Wqkv = (const float*)d_in[1];
  const float* Wo   = (const float*)d_in[2];
  const float* log_xi        = (const float*)d_in[3];
  const float* pi_gate_logit = (const float*)d_in[4];
  const float* e_gate_logit  = (const float*)d_in[5];

  u16* xb     = (u16*)d_ws;                 // 4096x1024
  u16* wqkvb  = xb + 4194304;               // 3072x1024
  u16* wob    = wqkvb + 3145728;            // 1024x1024
  u16* qkv    = wob + 1048576;              // 4096x3072
  u16* qrot   = qkv + 12582912;             // 32x2048x64
  u16* krot   = qrot + 4194304;
  u16* vt     = krot + 4194304;             // 32x64x2048
  u16* attno  = vt + 4194304;               // 4096x1024

  conv_kernel<<<4096, 256, 0, stream>>>(x, xb, 4194304);
  conv_kernel<<<3072, 256, 0, stream>>>(Wqkv, wqkvb, 3145728);
  conv_kernel<<<1024, 256, 0, stream>>>(Wo, wob, 1048576);

  gemm_bt<0><<<dim3(24, 32), 256, 0, stream>>>(xb, wqkvb, qkv, 3072, 1024);

  rope_kernel<<<dim3(32, 32), 256, 0, stream>>>(qkv, pi_gate_logit, qrot, krot, vt);

  attn_kernel<<<dim3(32, 16), 256, 0, stream>>>(qrot, krot, vt, log_xi, e_gate_logit, attno);

  gemm_bt<1><<<dim3(8, 32), 256, 0, stream>>>(attno, wob, d_out, 1024, 1024);
}